// Round 8
// baseline (145.397 us; speedup 1.0000x reference)
//
#include <hip/hip_runtime.h>
#include <hip/hip_fp16.h>

// BlockDiagonalLinear hyperbolic layer. Round 8: persistent-B K1.
//   K0 wrepack32: W f32 -> bf16 frags wb3[b][kf16][nt8][lane][8] (2 MiB ws)
//   K1: 512 WGs (2/CU), 4 waves. WG owns (block b = wg>>5, 256 rows).
//       Wave w holds B frags for nt={2w,2w+1} in 128 VGPRs, loaded ONCE.
//       Loop 8 tiles x 32 rows: prefetched coalesced A-stage -> shared
//       swizzled LDS (2x16 KiB dbuf), 16 ds_read_b128 + 32 MFMA/wave,
//       ssx (f32), ssp partials, mx'->fp16 rebounce in dead A buf ->
//       512B-contiguous stores. HBM stream continuous across tiles.
//   K2 gamma: reduce 16 ssx + 64 ssp partials -> per-row gamma.
//   K3 apply: streaming out = gam[row] * f16->f32(mx').

typedef __attribute__((ext_vector_type(8))) short short8;
typedef __attribute__((ext_vector_type(4))) float f32x4;
typedef __attribute__((ext_vector_type(16))) float f32x16;

__device__ __forceinline__ ushort f2bf(float f) {
  uint u = __float_as_uint(f);
  return (ushort)((u + 0x7fffu + ((u >> 16) & 1u)) >> 16);  // RNE
}

__device__ __forceinline__ float gamma_of(float sx, float s2) {
  const float xnorm = sqrtf(sx);
  const float un = fmaxf(xnorm, 1e-5f);
  const float a0 = 0.1f * un;
  const float th = tanhf(fminf(a0, 15.f));
  const float c = th / a0;             // h = c * x
  const float hn = th * (xnorm / a0);  // ||h||
  const float xn = fmaxf(hn, 1e-5f);
  const float sp = sqrtf(s2);          // ||mx'||
  float gt = 0.f;
  if (sp > 0.f) {
    const float s = c * sp;  // ||mx||
    const float xc = fminf(0.1f * xn, 1.f - 1e-5f);
    const float at = 0.5f * logf((1.f + xc) / (1.f - xc));  // artanh
    const float t = (s / xn) * at;
    const float tn = tanhf(fminf(t, 15.f));
    const float alpha = tn / (0.1f * s);  // res_c = alpha * mx
    const float rn = tn * 10.f;           // ||res_c||
    const float nrm = fmaxf(rn, 1e-5f);
    const float proj = (nrm > 9.99f) ? (9.99f / nrm) : 1.f;  // _project
    const float yn = fmaxf(rn * proj, 1e-5f);
    const float yc = fminf(0.1f * yn, 1.f - 1e-5f);
    const float at2 = 0.5f * logf((1.f + yc) / (1.f - yc));
    gt = c * alpha * proj * (at2 / (0.1f * yn));  // logmap0 + fold of c
  }
  return gt;
}

// K0: repack for 32x32x16. frag(b,kf,nt): lane l, j -> W[b][nt*32+(l&31)][kf*16+(l>>5)*8+j]
__global__ __launch_bounds__(256) void wrepack32(const float* __restrict__ w,
                                                 ushort* __restrict__ wb3) {
  int idx = blockIdx.x * 256 + threadIdx.x;  // 131072
  int lane = idx & 63;
  int nt = (idx >> 6) & 7;
  int kf = (idx >> 9) & 15;
  int b = idx >> 13;
  int n = nt * 32 + (lane & 31);
  int k0 = kf * 16 + (lane >> 5) * 8;
  const float* src = w + ((size_t)b << 16) + (size_t)n * 256 + k0;
  float4 v0 = *reinterpret_cast<const float4*>(src);
  float4 v1 = *reinterpret_cast<const float4*>(src + 4);
  uint4 p;
  p.x = (uint)f2bf(v0.x) | ((uint)f2bf(v0.y) << 16);
  p.y = (uint)f2bf(v0.z) | ((uint)f2bf(v0.w) << 16);
  p.z = (uint)f2bf(v1.x) | ((uint)f2bf(v1.y) << 16);
  p.w = (uint)f2bf(v1.z) | ((uint)f2bf(v1.w) << 16);
  reinterpret_cast<uint4*>(wb3)[idx] = p;
}

// K1: 512 WGs = 16 blocks x 32 row-groups; 256 thr (4 waves); 256 rows/WG.
__global__ __launch_bounds__(256, 2) void k1_kernel(const float* __restrict__ x,
                                                    const ushort* __restrict__ wb3,
                                                    float* __restrict__ ssxP,
                                                    float* __restrict__ sspP,
                                                    ushort* __restrict__ mxw) {
  __shared__ __align__(16) ushort Abuf[2][32 * 256];  // 2 x 16 KiB

  const int tid = threadIdx.x;
  const int w = tid >> 6;
  const int l = tid & 63;
  const int lo = l & 31;
  const int hi = l >> 5;
  const int b = blockIdx.x >> 5;
  const int rg = blockIdx.x & 31;
  const size_t rowbase = (size_t)rg * 256;
  const ushort* bbase = wb3 + ((size_t)b << 16);

  // ---- B frags for nt = 2w, 2w+1: loaded ONCE (32 coalesced 1KB loads) ----
  short8 B0[16], B1[16];
#pragma unroll
  for (int kf = 0; kf < 16; ++kf) {
    B0[kf] = *reinterpret_cast<const short8*>(bbase + (size_t)(kf * 8 + w * 2 + 0) * 512 + l * 8);
    B1[kf] = *reinterpret_cast<const short8*>(bbase + (size_t)(kf * 8 + w * 2 + 1) * 512 + l * 8);
  }

  // ---- A tile-0 prefetch: wave w stages rows w*8..w*8+7 ----
  float4 va[8];
#pragma unroll
  for (int r = 0; r < 8; ++r)
    va[r] = *reinterpret_cast<const float4*>(x + (rowbase + w * 8 + r) * 4096 + b * 256 + l * 4);

  for (int t = 0; t < 8; ++t) {
    char* A = reinterpret_cast<char*>(Abuf[t & 1]);

    // ---- write A (bf16, swizzled) + ssx from f32 registers ----
#pragma unroll
    for (int r = 0; r < 8; ++r) {
      const float4 v = va[r];
      const int lrow = w * 8 + r;
      uint2 p;
      p.x = (uint)f2bf(v.x) | ((uint)f2bf(v.y) << 16);
      p.y = (uint)f2bf(v.z) | ((uint)f2bf(v.w) << 16);
      uint byte = ((uint)(lrow * 512 + l * 8)) ^ ((uint)(r & 7) << 4);
      *reinterpret_cast<uint2*>(A + byte) = p;
      float ss = v.x * v.x + v.y * v.y + v.z * v.z + v.w * v.w;
#pragma unroll
      for (int m = 32; m; m >>= 1) ss += __shfl_xor(ss, m, 64);
      if (l == 0) ssxP[b * 8192 + rowbase + t * 32 + lrow] = ss;
    }
    __syncthreads();  // A[t] visible; also protects vs tile t-2 readers

    // ---- issue next tile's A loads (overlap with compute below) ----
    if (t < 7) {
#pragma unroll
      for (int r = 0; r < 8; ++r)
        va[r] = *reinterpret_cast<const float4*>(
            x + (rowbase + (t + 1) * 32 + w * 8 + r) * 4096 + b * 256 + l * 4);
    }

    // ---- compute: 16 kf x (A ds_read_b128 + 2 MFMA with reg-B) ----
    f32x16 a0, a1;
#pragma unroll
    for (int r = 0; r < 16; ++r) { a0[r] = 0.f; a1[r] = 0.f; }
#pragma unroll
    for (int kf = 0; kf < 16; ++kf) {
      uint ab = ((uint)(lo * 512 + kf * 32 + hi * 16)) ^ ((uint)(lo & 7) << 4);
      short8 af = *reinterpret_cast<const short8*>(A + ab);
      a0 = __builtin_amdgcn_mfma_f32_32x32x16_bf16(af, B0[kf], a0, 0, 0, 0);
      a1 = __builtin_amdgcn_mfma_f32_32x32x16_bf16(af, B1[kf], a1, 0, 0, 0);
    }

    // ---- ssp partials over this wave's 64 cols ----
    {
      float s[16];
#pragma unroll
      for (int r = 0; r < 16; ++r) s[r] = a0[r] * a0[r] + a1[r] * a1[r];
#pragma unroll
      for (int m = 1; m < 32; m <<= 1)
#pragma unroll
        for (int r = 0; r < 16; ++r) s[r] += __shfl_xor(s[r], m, 64);
      if (lo == 0) {
#pragma unroll
        for (int r = 0; r < 16; ++r) {
          const int row = (r & 3) + 8 * (r >> 2) + 4 * hi;
          sspP[(size_t)(b * 4 + w) * 8192 + rowbase + t * 32 + row] = s[r];
        }
      }
    }
    __syncthreads();  // all waves done reading A[t]

    // ---- mx' fp16 rebounce into dead A buffer (linear layout) ----
#pragma unroll
    for (int r = 0; r < 16; ++r) {
      const int row = (r & 3) + 8 * (r >> 2) + 4 * hi;
      *reinterpret_cast<__half*>(A + row * 512 + (w * 64 + lo) * 2) = __float2half(a0[r]);
      *reinterpret_cast<__half*>(A + row * 512 + (w * 64 + 32 + lo) * 2) = __float2half(a1[r]);
    }
    __syncthreads();

    // ---- coalesced mx' store: 512B contiguous per row ----
#pragma unroll
    for (int r = 0; r < 8; ++r) {
      const int lrow = w * 8 + r;
      uint2 v = *reinterpret_cast<const uint2*>(A + lrow * 512 + l * 8);
      *reinterpret_cast<uint2*>(mxw + ((size_t)b * 8192 + rowbase + t * 32 + lrow) * 256 + l * 4) = v;
    }
  }
}

// K2: gamma per row (16 ssx partials, 64 ssp partials).
__global__ __launch_bounds__(256) void gamma_kernel(const float* __restrict__ ssxP,
                                                    const float* __restrict__ sspP,
                                                    float* __restrict__ gam) {
  const int row = blockIdx.x * 256 + threadIdx.x;
  float sx = 0.f, s2 = 0.f;
#pragma unroll
  for (int bb = 0; bb < 16; ++bb) sx += ssxP[bb * 8192 + row];
#pragma unroll
  for (int p = 0; p < 64; ++p) s2 += sspP[(size_t)p * 8192 + row];
  gam[row] = gamma_of(sx, s2);
}

// K3: out = gam[row] * mx' (fp16->f32). Dense streaming.
__global__ __launch_bounds__(256) void k3_kernel(const ushort* __restrict__ mxw,
                                                 const float* __restrict__ gam,
                                                 float* __restrict__ out) {
  const int t0 = blockIdx.x * 256 + threadIdx.x;
#pragma unroll 4
  for (int it = 0; it < 16; ++it) {
    const int Q = t0 + it * 524288;  // quad index over 16*8192*64
    const int b = Q >> 19;
    const int r = (Q >> 6) & 8191;
    const int c = (Q & 63) << 2;
    uint2 p = *reinterpret_cast<const uint2*>(mxw + ((size_t)Q << 2));
    const float gv = gam[r];
    __half2 h0 = *reinterpret_cast<__half2*>(&p.x);
    __half2 h1 = *reinterpret_cast<__half2*>(&p.y);
    float2 f0 = __half22float2(h0);
    float2 f1 = __half22float2(h1);
    float4 o;
    o.x = f0.x * gv;
    o.y = f0.y * gv;
    o.z = f1.x * gv;
    o.w = f1.y * gv;
    *reinterpret_cast<float4*>(out + (size_t)r * 4096 + b * 256 + c) = o;
  }
}

// -------- Fallback: round-3 fused kernel + its 16x16 repack (2 MiB ws) --------
__global__ __launch_bounds__(256) void wrepack16(const float* __restrict__ w,
                                                 ushort* __restrict__ wb2) {
  int idx = blockIdx.x * blockDim.x + threadIdx.x;  // 131072
  int lane = idx & 63;
  int nt = (idx >> 6) & 15;
  int kf = (idx >> 10) & 7;
  int blk = idx >> 13;
  int g = lane >> 4, q = lane & 15;
  const float* src = w + ((size_t)blk << 16) + (size_t)(nt * 16 + q) * 256 + kf * 32 + g * 8;
  float4 v0 = *reinterpret_cast<const float4*>(src);
  float4 v1 = *reinterpret_cast<const float4*>(src + 4);
  uint4 p;
  p.x = (uint)f2bf(v0.x) | ((uint)f2bf(v0.y) << 16);
  p.y = (uint)f2bf(v0.z) | ((uint)f2bf(v0.w) << 16);
  p.z = (uint)f2bf(v1.x) | ((uint)f2bf(v1.y) << 16);
  p.w = (uint)f2bf(v1.z) | ((uint)f2bf(v1.w) << 16);
  reinterpret_cast<uint4*>(wb2)[idx] = p;
}

__global__ __launch_bounds__(1024, 4) void hyp_fused(const float* __restrict__ x,
                                                     const ushort* __restrict__ wb2,
                                                     float* __restrict__ out) {
  __shared__ ushort xs[16 * 4096];
  __shared__ float ssxp[16];
  __shared__ float sspm[16][16];
  __shared__ float gamv[16];
  const int tid = threadIdx.x;
  const int w = tid >> 6;
  const int lane = tid & 63;
  const int g = lane >> 4, q = lane & 15;
  const size_t rowbase = (size_t)blockIdx.x * 16;
  {
    const float4* xr = reinterpret_cast<const float4*>(x + (rowbase + w) * 4096);
    char* xrow = reinterpret_cast<char*>(xs);
    const uint sw = (uint)(w & 7) << 4;
    float ss = 0.f;
#pragma unroll
    for (int chunk = 0; chunk < 16; ++chunk) {
      float4 v = xr[chunk * 64 + lane];
      ss += v.x * v.x + v.y * v.y + v.z * v.z + v.w * v.w;
      uint2 p;
      p.x = (uint)f2bf(v.x) | ((uint)f2bf(v.y) << 16);
      p.y = (uint)f2bf(v.z) | ((uint)f2bf(v.w) << 16);
      uint byte = ((uint)(w * 8192 + (chunk * 64 + lane) * 8)) ^ sw;
      *reinterpret_cast<uint2*>(xrow + byte) = p;
    }
#pragma unroll
    for (int m = 32; m; m >>= 1) ss += __shfl_xor(ss, m, 64);
    if (lane == 0) ssxp[w] = ss;
  }
  __syncthreads();
  f32x4 acc[16];
#pragma unroll
  for (int nt = 0; nt < 16; ++nt) acc[nt] = (f32x4){0.f, 0.f, 0.f, 0.f};
  for (int kf = 0; kf < 8; ++kf) {
    uint abyte = ((uint)(q * 8192 + w * 512 + kf * 64 + g * 16)) ^ ((uint)(q & 7) << 4);
    short8 afr = *reinterpret_cast<const short8*>(reinterpret_cast<const char*>(xs) + abyte);
    const ushort* bkf = wb2 + ((((size_t)w * 8 + kf) * 16) << 9) + (lane << 3);
#pragma unroll
    for (int nt = 0; nt < 16; ++nt) {
      short8 bfr = *reinterpret_cast<const short8*>(bkf + (nt << 9));
      acc[nt] = __builtin_amdgcn_mfma_f32_16x16x32_bf16(afr, bfr, acc[nt], 0, 0, 0);
    }
  }
  {
    float s0 = 0.f, s1 = 0.f, s2a = 0.f, s3 = 0.f;
#pragma unroll
    for (int nt = 0; nt < 16; ++nt) {
      f32x4 a = acc[nt];
      s0 += a[0] * a[0]; s1 += a[1] * a[1]; s2a += a[2] * a[2]; s3 += a[3] * a[3];
    }
#pragma unroll
    for (int m = 1; m < 16; m <<= 1) {
      s0 += __shfl_xor(s0, m, 64); s1 += __shfl_xor(s1, m, 64);
      s2a += __shfl_xor(s2a, m, 64); s3 += __shfl_xor(s3, m, 64);
    }
    if (q == 0) {
      sspm[w][g * 4 + 0] = s0; sspm[w][g * 4 + 1] = s1;
      sspm[w][g * 4 + 2] = s2a; sspm[w][g * 4 + 3] = s3;
    }
  }
  __syncthreads();
  if (tid < 16) {
    float s2 = 0.f;
#pragma unroll
    for (int ww = 0; ww < 16; ++ww) s2 += sspm[ww][tid];
    gamv[tid] = gamma_of(ssxp[tid], s2);
  }
  __syncthreads();
  float gr[4];
#pragma unroll
  for (int j = 0; j < 4; ++j) gr[j] = gamv[g * 4 + j];
  float* orow = out + rowbase * 4096 + w * 256;
#pragma unroll
  for (int nt = 0; nt < 16; ++nt) {
    const int col = nt * 16 + q;
    f32x4 a = acc[nt];
#pragma unroll
    for (int j = 0; j < 4; ++j) orow[(size_t)(g * 4 + j) * 4096 + col] = gr[j] * a[j];
  }
}

extern "C" void kernel_launch(void* const* d_in, const int* in_sizes, int n_in,
                              void* d_out, int out_size, void* d_ws, size_t ws_size,
                              hipStream_t stream) {
  const float* x = (const float*)d_in[0];  // [4,2048,4096] f32
  const float* w = (const float*)d_in[1];  // [16,256,256] f32
  float* out = (float*)d_out;              // [4,2048,4096] f32

  const size_t WB = (size_t)2 << 20;                 // wb3/wb2: 2 MiB @ 0
  const size_t SSX_OFF = WB;                         // ssxP: 512 KiB
  const size_t SSP_OFF = WB + ((size_t)512 << 10);   // sspP: 2 MiB (64 x 8192 f32)
  const size_t MXW_OFF = SSP_OFF + ((size_t)2 << 20);  // mxw: 64 MiB
  const size_t GAM_OFF = 0;                          // gam overlaps wb3 (dead after K1)
  const size_t NEED = MXW_OFF + (size_t)16 * 8192 * 256 * 2;

  if (ws_size >= NEED) {
    ushort* wb3 = (ushort*)d_ws;
    float* ssxP = (float*)((char*)d_ws + SSX_OFF);
    float* sspP = (float*)((char*)d_ws + SSP_OFF);
    float* gamv = (float*)((char*)d_ws + GAM_OFF);
    ushort* mxw = (ushort*)((char*)d_ws + MXW_OFF);
    wrepack32<<<512, 256, 0, stream>>>(w, wb3);
    k1_kernel<<<512, 256, 0, stream>>>(x, wb3, ssxP, sspP, mxw);
    gamma_kernel<<<32, 256, 0, stream>>>(ssxP, sspP, gamv);  // gamv clobbers wb3 (dead)
    k3_kernel<<<2048, 256, 0, stream>>>(mxw, gamv, out);
  } else if (ws_size >= WB) {
    ushort* wb2 = (ushort*)d_ws;
    wrepack16<<<512, 256, 0, stream>>>(w, wb2);
    hyp_fused<<<512, 1024, 0, stream>>>(x, wb2, out);
  }
}

// Round 9
// 138.742 us; speedup vs baseline: 1.0480x; 1.0480x over previous
//
#include <hip/hip_runtime.h>
#include <hip/hip_fp16.h>

// BlockDiagonalLinear hyperbolic layer. Round 9: ZERO-LDS, ZERO-BARRIER K1.
//   K0 wrepack32: W f32 -> bf16 frags wb3[b][kf16][nt8][lane][8] (2 MiB ws)
//   K1: 512 WGs (4 waves). WG = (block b, 256 rows); wave w holds B for
//       nt={2w,2w+1} in 128 VGPRs (loaded once). Loop 8 tiles x 32 rows:
//       A-fragments loaded DIRECTLY from global x (32B/lane contiguous,
//       4-kf batches, 8 loads in flight), MFMA from regs, ssx (f32, w0),
//       ssp via intra-half shfl, mx' packed fp16 -> FRAGMENT-layout chunk
//       store (4x dwordx4 contiguous). No LDS. No __syncthreads.
//   K2 gamma: reduce 16 ssx + 64 ssp partials -> per-row gamma.
//   K3 apply: read frag chunks, out[row][col] = gam[row] * fp16val,
//       2x128B-segment stores, gamma L1-hot.

typedef __attribute__((ext_vector_type(8))) short short8;
typedef __attribute__((ext_vector_type(4))) float f32x4;
typedef __attribute__((ext_vector_type(16))) float f32x16;

__device__ __forceinline__ ushort f2bf(float f) {
  uint u = __float_as_uint(f);
  return (ushort)((u + 0x7fffu + ((u >> 16) & 1u)) >> 16);  // RNE
}

__device__ __forceinline__ float gamma_of(float sx, float s2) {
  const float xnorm = sqrtf(sx);
  const float un = fmaxf(xnorm, 1e-5f);
  const float a0 = 0.1f * un;
  const float th = tanhf(fminf(a0, 15.f));
  const float c = th / a0;             // h = c * x
  const float hn = th * (xnorm / a0);  // ||h||
  const float xn = fmaxf(hn, 1e-5f);
  const float sp = sqrtf(s2);          // ||mx'||
  float gt = 0.f;
  if (sp > 0.f) {
    const float s = c * sp;  // ||mx||
    const float xc = fminf(0.1f * xn, 1.f - 1e-5f);
    const float at = 0.5f * logf((1.f + xc) / (1.f - xc));  // artanh
    const float t = (s / xn) * at;
    const float tn = tanhf(fminf(t, 15.f));
    const float alpha = tn / (0.1f * s);  // res_c = alpha * mx
    const float rn = tn * 10.f;           // ||res_c||
    const float nrm = fmaxf(rn, 1e-5f);
    const float proj = (nrm > 9.99f) ? (9.99f / nrm) : 1.f;  // _project
    const float yn = fmaxf(rn * proj, 1e-5f);
    const float yc = fminf(0.1f * yn, 1.f - 1e-5f);
    const float at2 = 0.5f * logf((1.f + yc) / (1.f - yc));
    gt = c * alpha * proj * (at2 / (0.1f * yn));  // logmap0 + fold of c
  }
  return gt;
}

// K0: repack for 32x32x16. frag(b,kf,nt): lane l, j -> W[b][nt*32+(l&31)][kf*16+(l>>5)*8+j]
__global__ __launch_bounds__(256) void wrepack32(const float* __restrict__ w,
                                                 ushort* __restrict__ wb3) {
  int idx = blockIdx.x * 256 + threadIdx.x;  // 131072
  int lane = idx & 63;
  int nt = (idx >> 6) & 7;
  int kf = (idx >> 9) & 15;
  int b = idx >> 13;
  int n = nt * 32 + (lane & 31);
  int k0 = kf * 16 + (lane >> 5) * 8;
  const float* src = w + ((size_t)b << 16) + (size_t)n * 256 + k0;
  float4 v0 = *reinterpret_cast<const float4*>(src);
  float4 v1 = *reinterpret_cast<const float4*>(src + 4);
  uint4 p;
  p.x = (uint)f2bf(v0.x) | ((uint)f2bf(v0.y) << 16);
  p.y = (uint)f2bf(v0.z) | ((uint)f2bf(v0.w) << 16);
  p.z = (uint)f2bf(v1.x) | ((uint)f2bf(v1.y) << 16);
  p.w = (uint)f2bf(v1.z) | ((uint)f2bf(v1.w) << 16);
  reinterpret_cast<uint4*>(wb3)[idx] = p;
}

// K1: 512 WGs = 16 blocks x 32 row-groups; 256 thr (4 waves); 256 rows/WG.
__global__ __launch_bounds__(256, 2) void k1_kernel(const float* __restrict__ x,
                                                    const ushort* __restrict__ wb3,
                                                    float* __restrict__ ssxP,
                                                    float* __restrict__ sspP,
                                                    ushort* __restrict__ mxw) {
  const int tid = threadIdx.x;
  const int w = tid >> 6;
  const int l = tid & 63;
  const int lo = l & 31;
  const int hi = l >> 5;
  const int b = blockIdx.x & 15;
  const int rg = blockIdx.x >> 4;  // 0..31
  const ushort* bbase = wb3 + ((size_t)b << 16);

  // ---- Persistent B: nt = 2w, 2w+1, all 16 kf (32 coalesced 1KB loads) ----
  short8 B0[16], B1[16];
#pragma unroll
  for (int kf = 0; kf < 16; ++kf) {
    B0[kf] = *reinterpret_cast<const short8*>(bbase + (size_t)(kf * 8 + w * 2 + 0) * 512 + l * 8);
    B1[kf] = *reinterpret_cast<const short8*>(bbase + (size_t)(kf * 8 + w * 2 + 1) * 512 + l * 8);
  }

  for (int t = 0; t < 8; ++t) {
    const int rt = rg * 8 + t;  // global row-tile 0..255
    const float* abase = x + ((size_t)rt * 32 + lo) * 4096 + b * 256 + hi * 8;

    f32x16 a0, a1;
#pragma unroll
    for (int r = 0; r < 16; ++r) { a0[r] = 0.f; a1[r] = 0.f; }
    float ssl = 0.f;

    // ---- A direct from global: 4 batches of 4 kf (8 loads in flight) ----
#pragma unroll
    for (int bb4 = 0; bb4 < 4; ++bb4) {
      float4 va[8];
#pragma unroll
      for (int k4 = 0; k4 < 4; ++k4) {
        const int kf = bb4 * 4 + k4;
        va[k4 * 2 + 0] = *reinterpret_cast<const float4*>(abase + kf * 16);
        va[k4 * 2 + 1] = *reinterpret_cast<const float4*>(abase + kf * 16 + 4);
      }
      if (w == 0) {
#pragma unroll
        for (int i = 0; i < 8; ++i)
          ssl += va[i].x * va[i].x + va[i].y * va[i].y + va[i].z * va[i].z + va[i].w * va[i].w;
      }
#pragma unroll
      for (int k4 = 0; k4 < 4; ++k4) {
        const int kf = bb4 * 4 + k4;
        const float4 v0 = va[k4 * 2], v1 = va[k4 * 2 + 1];
        short8 af;
        af[0] = (short)f2bf(v0.x); af[1] = (short)f2bf(v0.y);
        af[2] = (short)f2bf(v0.z); af[3] = (short)f2bf(v0.w);
        af[4] = (short)f2bf(v1.x); af[5] = (short)f2bf(v1.y);
        af[6] = (short)f2bf(v1.z); af[7] = (short)f2bf(v1.w);
        a0 = __builtin_amdgcn_mfma_f32_32x32x16_bf16(af, B0[kf], a0, 0, 0, 0);
        a1 = __builtin_amdgcn_mfma_f32_32x32x16_bf16(af, B1[kf], a1, 0, 0, 0);
      }
    }

    // ---- ssx (wave 0 only; f32-exact): combine hi-halves, hi==0 stores ----
    if (w == 0) {
      ssl += __shfl_xor(ssl, 32, 64);
      if (hi == 0) ssxP[b * 8192 + rt * 32 + lo] = ssl;  // 128B contiguous
    }

    // ---- ssp partials: reduce across lo within each half (rows differ by hi) ----
    {
      float s[16];
#pragma unroll
      for (int r = 0; r < 16; ++r) s[r] = a0[r] * a0[r] + a1[r] * a1[r];
#pragma unroll
      for (int m = 1; m < 32; m <<= 1)
#pragma unroll
        for (int r = 0; r < 16; ++r) s[r] += __shfl_xor(s[r], m, 64);
      if (lo == 0) {
#pragma unroll
        for (int r = 0; r < 16; ++r) {
          const int rr = (r & 3) + 8 * (r >> 2) + 4 * hi;
          sspP[(size_t)(b * 4 + w) * 8192 + rt * 32 + rr] = s[r];
        }
      }
    }

    // ---- pack fp16 + fragment-layout chunk store (fully contiguous) ----
    {
      uint wds[16];
#pragma unroll
      for (int j = 0; j < 8; ++j) {
        __half2 h0 = __floats2half2_rn(a0[2 * j], a0[2 * j + 1]);
        __half2 h1 = __floats2half2_rn(a1[2 * j], a1[2 * j + 1]);
        wds[j] = *reinterpret_cast<uint*>(&h0);
        wds[8 + j] = *reinterpret_cast<uint*>(&h1);
      }
      ushort* dst = mxw + (size_t)((b * 256 + rt) * 4 + w) * 2048;
#pragma unroll
      for (int i = 0; i < 4; ++i) {
        uint4 p;
        p.x = wds[i * 4 + 0]; p.y = wds[i * 4 + 1];
        p.z = wds[i * 4 + 2]; p.w = wds[i * 4 + 3];
        *reinterpret_cast<uint4*>(dst + (size_t)(i * 64 + l) * 8) = p;  // 1KB/instr
      }
    }
  }
}

// K2: gamma per row (16 ssx partials, 64 ssp partials).
__global__ __launch_bounds__(256) void gamma_kernel(const float* __restrict__ ssxP,
                                                    const float* __restrict__ sspP,
                                                    float* __restrict__ gam) {
  const int row = blockIdx.x * 256 + threadIdx.x;
  float sx = 0.f, s2 = 0.f;
#pragma unroll
  for (int bb = 0; bb < 16; ++bb) sx += ssxP[bb * 8192 + row];
#pragma unroll
  for (int p = 0; p < 64; ++p) s2 += sspP[(size_t)p * 8192 + row];
  gam[row] = gamma_of(sx, s2);
}

// K3: read frag chunks, scale by gam[row], store to out (2x128B segs/instr).
__global__ __launch_bounds__(256) void k3_kernel(const ushort* __restrict__ mxw,
                                                 const float* __restrict__ gam,
                                                 float* __restrict__ out) {
  const int wt = blockIdx.x * 4 + (threadIdx.x >> 6);  // 0..16383
  const int l = threadIdx.x & 63;
  const int lo = l & 31;
  const int hi = l >> 5;
  const int w = wt & 3;
  const int rt = (wt >> 2) & 255;
  const int b = wt >> 10;
  const ushort* src = mxw + (size_t)wt * 2048;
  uint4 p[4];
#pragma unroll
  for (int i = 0; i < 4; ++i)
    p[i] = *reinterpret_cast<const uint4*>(src + (size_t)(i * 64 + l) * 8);
  const int colbase = b * 256 + w * 64 + lo;  // a0 col; a1 col = +32
  const int rowb = rt * 32 + 4 * hi;
  const uint* pw = reinterpret_cast<const uint*>(p);
#pragma unroll
  for (int j = 0; j < 8; ++j) {
    const int r0 = 2 * j, r1 = 2 * j + 1;
    const int R0 = rowb + (r0 & 3) + 8 * (r0 >> 2);
    const int R1 = rowb + (r1 & 3) + 8 * (r1 >> 2);
    uint w0 = pw[j];
    uint w1 = pw[8 + j];
    float2 f0 = __half22float2(*reinterpret_cast<__half2*>(&w0));
    float2 f1 = __half22float2(*reinterpret_cast<__half2*>(&w1));
    const float g0 = gam[R0], g1 = gam[R1];
    out[(size_t)R0 * 4096 + colbase] = f0.x * g0;
    out[(size_t)R1 * 4096 + colbase] = f0.y * g1;
    out[(size_t)R0 * 4096 + colbase + 32] = f1.x * g0;
    out[(size_t)R1 * 4096 + colbase + 32] = f1.y * g1;
  }
}

// -------- Fallback: round-3 fused kernel + its 16x16 repack (2 MiB ws) --------
__global__ __launch_bounds__(256) void wrepack16(const float* __restrict__ w,
                                                 ushort* __restrict__ wb2) {
  int idx = blockIdx.x * blockDim.x + threadIdx.x;  // 131072
  int lane = idx & 63;
  int nt = (idx >> 6) & 15;
  int kf = (idx >> 10) & 7;
  int blk = idx >> 13;
  int g = lane >> 4, q = lane & 15;
  const float* src = w + ((size_t)blk << 16) + (size_t)(nt * 16 + q) * 256 + kf * 32 + g * 8;
  float4 v0 = *reinterpret_cast<const float4*>(src);
  float4 v1 = *reinterpret_cast<const float4*>(src + 4);
  uint4 p;
  p.x = (uint)f2bf(v0.x) | ((uint)f2bf(v0.y) << 16);
  p.y = (uint)f2bf(v0.z) | ((uint)f2bf(v0.w) << 16);
  p.z = (uint)f2bf(v1.x) | ((uint)f2bf(v1.y) << 16);
  p.w = (uint)f2bf(v1.z) | ((uint)f2bf(v1.w) << 16);
  reinterpret_cast<uint4*>(wb2)[idx] = p;
}

__global__ __launch_bounds__(1024, 4) void hyp_fused(const float* __restrict__ x,
                                                     const ushort* __restrict__ wb2,
                                                     float* __restrict__ out) {
  __shared__ ushort xs[16 * 4096];
  __shared__ float ssxp[16];
  __shared__ float sspm[16][16];
  __shared__ float gamv[16];
  const int tid = threadIdx.x;
  const int w = tid >> 6;
  const int lane = tid & 63;
  const int g = lane >> 4, q = lane & 15;
  const size_t rowbase = (size_t)blockIdx.x * 16;
  {
    const float4* xr = reinterpret_cast<const float4*>(x + (rowbase + w) * 4096);
    char* xrow = reinterpret_cast<char*>(xs);
    const uint sw = (uint)(w & 7) << 4;
    float ss = 0.f;
#pragma unroll
    for (int chunk = 0; chunk < 16; ++chunk) {
      float4 v = xr[chunk * 64 + lane];
      ss += v.x * v.x + v.y * v.y + v.z * v.z + v.w * v.w;
      uint2 p;
      p.x = (uint)f2bf(v.x) | ((uint)f2bf(v.y) << 16);
      p.y = (uint)f2bf(v.z) | ((uint)f2bf(v.w) << 16);
      uint byte = ((uint)(w * 8192 + (chunk * 64 + lane) * 8)) ^ sw;
      *reinterpret_cast<uint2*>(xrow + byte) = p;
    }
#pragma unroll
    for (int m = 32; m; m >>= 1) ss += __shfl_xor(ss, m, 64);
    if (lane == 0) ssxp[w] = ss;
  }
  __syncthreads();
  f32x4 acc[16];
#pragma unroll
  for (int nt = 0; nt < 16; ++nt) acc[nt] = (f32x4){0.f, 0.f, 0.f, 0.f};
  for (int kf = 0; kf < 8; ++kf) {
    uint abyte = ((uint)(q * 8192 + w * 512 + kf * 64 + g * 16)) ^ ((uint)(q & 7) << 4);
    short8 afr = *reinterpret_cast<const short8*>(reinterpret_cast<const char*>(xs) + abyte);
    const ushort* bkf = wb2 + ((((size_t)w * 8 + kf) * 16) << 9) + (lane << 3);
#pragma unroll
    for (int nt = 0; nt < 16; ++nt) {
      short8 bfr = *reinterpret_cast<const short8*>(bkf + (nt << 9));
      acc[nt] = __builtin_amdgcn_mfma_f32_16x16x32_bf16(afr, bfr, acc[nt], 0, 0, 0);
    }
  }
  {
    float s0 = 0.f, s1 = 0.f, s2a = 0.f, s3 = 0.f;
#pragma unroll
    for (int nt = 0; nt < 16; ++nt) {
      f32x4 a = acc[nt];
      s0 += a[0] * a[0]; s1 += a[1] * a[1]; s2a += a[2] * a[2]; s3 += a[3] * a[3];
    }
#pragma unroll
    for (int m = 1; m < 16; m <<= 1) {
      s0 += __shfl_xor(s0, m, 64); s1 += __shfl_xor(s1, m, 64);
      s2a += __shfl_xor(s2a, m, 64); s3 += __shfl_xor(s3, m, 64);
    }
    if (q == 0) {
      sspm[w][g * 4 + 0] = s0; sspm[w][g * 4 + 1] = s1;
      sspm[w][g * 4 + 2] = s2a; sspm[w][g * 4 + 3] = s3;
    }
  }
  __syncthreads();
  if (tid < 16) {
    float s2 = 0.f;
#pragma unroll
    for (int ww = 0; ww < 16; ++ww) s2 += sspm[ww][tid];
    gamv[tid] = gamma_of(ssxp[tid], s2);
  }
  __syncthreads();
  float gr[4];
#pragma unroll
  for (int j = 0; j < 4; ++j) gr[j] = gamv[g * 4 + j];
  float* orow = out + rowbase * 4096 + w * 256;
#pragma unroll
  for (int nt = 0; nt < 16; ++nt) {
    const int col = nt * 16 + q;
    f32x4 a = acc[nt];
#pragma unroll
    for (int j = 0; j < 4; ++j) orow[(size_t)(g * 4 + j) * 4096 + col] = gr[j] * a[j];
  }
}

extern "C" void kernel_launch(void* const* d_in, const int* in_sizes, int n_in,
                              void* d_out, int out_size, void* d_ws, size_t ws_size,
                              hipStream_t stream) {
  const float* x = (const float*)d_in[0];  // [4,2048,4096] f32
  const float* w = (const float*)d_in[1];  // [16,256,256] f32
  float* out = (float*)d_out;              // [4,2048,4096] f32

  const size_t WB = (size_t)2 << 20;                   // wb3/wb2: 2 MiB @ 0
  const size_t SSX_OFF = WB;                           // ssxP: 512 KiB
  const size_t SSP_OFF = WB + ((size_t)512 << 10);     // sspP: 2 MiB (64 x 8192 f32)
  const size_t MXW_OFF = SSP_OFF + ((size_t)2 << 20);  // mxw: 64 MiB (frag layout)
  const size_t NEED = MXW_OFF + (size_t)16 * 8192 * 256 * 2;

  if (ws_size >= NEED) {
    ushort* wb3 = (ushort*)d_ws;
    float* ssxP = (float*)((char*)d_ws + SSX_OFF);
    float* sspP = (float*)((char*)d_ws + SSP_OFF);
    float* gamv = (float*)d_ws;  // overlaps wb3 (dead after K1)
    ushort* mxw = (ushort*)((char*)d_ws + MXW_OFF);
    wrepack32<<<512, 256, 0, stream>>>(w, wb3);
    k1_kernel<<<512, 256, 0, stream>>>(x, wb3, ssxP, sspP, mxw);
    gamma_kernel<<<32, 256, 0, stream>>>(ssxP, sspP, gamv);  // gamv clobbers wb3 (dead)
    k3_kernel<<<4096, 256, 0, stream>>>(mxw, gamv, out);
  } else if (ws_size >= WB) {
    ushort* wb2 = (ushort*)d_ws;
    wrepack16<<<512, 256, 0, stream>>>(w, wb2);
    hyp_fused<<<512, 1024, 0, stream>>>(x, wb2, out);
  }
}

// Round 10
// 138.723 us; speedup vs baseline: 1.0481x; 1.0001x over previous
//
#include <hip/hip_runtime.h>
#include <hip/hip_fp16.h>
#include <hip/hip_cooperative_groups.h>

namespace cg = cooperative_groups;

// BlockDiagonalLinear hyperbolic layer. Round 10: cooperative single-pass.
//   K0 wrepack32: W f32 -> bf16 frags wb3[b][kf16][nt8][lane][8] (2 MiB ws)
//   Kcoop: 512 WGs x 512 thr (2/CU co-resident). WG=(b, 256 rows); wave w
//     owns nt=w: B = 16 short8 = 64 VGPR (persistent). 8 tiles x 32 rows:
//     A f32->bf16 staged via 2x16KiB swizzled LDS dbuf (prefetch overlaps
//     MFMA), 16 kf x 1 MFMA 32x32x16, mx' packed fp16 in 64 VGPR, ssx/ssp
//     partials -> ws. grid.sync(). gamma per row (L2-hot partials). Epilogue:
//     out = gam * mx' from registers. HBM = x once + out once (~256 MB).
//   Fallback (occupancy < 2 WG/CU): round-9 4-kernel pipeline.

typedef __attribute__((ext_vector_type(8))) short short8;
typedef __attribute__((ext_vector_type(16))) float f32x16;

__device__ __forceinline__ ushort f2bf(float f) {
  uint u = __float_as_uint(f);
  return (ushort)((u + 0x7fffu + ((u >> 16) & 1u)) >> 16);  // RNE
}

__device__ __forceinline__ float gamma_of(float sx, float s2) {
  const float xnorm = sqrtf(sx);
  const float un = fmaxf(xnorm, 1e-5f);
  const float a0 = 0.1f * un;
  const float th = tanhf(fminf(a0, 15.f));
  const float c = th / a0;             // h = c * x
  const float hn = th * (xnorm / a0);  // ||h||
  const float xn = fmaxf(hn, 1e-5f);
  const float sp = sqrtf(s2);          // ||mx'||
  float gt = 0.f;
  if (sp > 0.f) {
    const float s = c * sp;  // ||mx||
    const float xc = fminf(0.1f * xn, 1.f - 1e-5f);
    const float at = 0.5f * logf((1.f + xc) / (1.f - xc));  // artanh
    const float t = (s / xn) * at;
    const float tn = tanhf(fminf(t, 15.f));
    const float alpha = tn / (0.1f * s);  // res_c = alpha * mx
    const float rn = tn * 10.f;           // ||res_c||
    const float nrm = fmaxf(rn, 1e-5f);
    const float proj = (nrm > 9.99f) ? (9.99f / nrm) : 1.f;  // _project
    const float yn = fmaxf(rn * proj, 1e-5f);
    const float yc = fminf(0.1f * yn, 1.f - 1e-5f);
    const float at2 = 0.5f * logf((1.f + yc) / (1.f - yc));
    gt = c * alpha * proj * (at2 / (0.1f * yn));  // logmap0 + fold of c
  }
  return gt;
}

// K0: repack for 32x32x16. frag(b,kf,nt): lane l, j -> W[b][nt*32+(l&31)][kf*16+(l>>5)*8+j]
__global__ __launch_bounds__(256) void wrepack32(const float* __restrict__ w,
                                                 ushort* __restrict__ wb3) {
  int idx = blockIdx.x * 256 + threadIdx.x;  // 131072
  int lane = idx & 63;
  int nt = (idx >> 6) & 7;
  int kf = (idx >> 9) & 15;
  int b = idx >> 13;
  int n = nt * 32 + (lane & 31);
  int k0 = kf * 16 + (lane >> 5) * 8;
  const float* src = w + ((size_t)b << 16) + (size_t)n * 256 + k0;
  float4 v0 = *reinterpret_cast<const float4*>(src);
  float4 v1 = *reinterpret_cast<const float4*>(src + 4);
  uint4 p;
  p.x = (uint)f2bf(v0.x) | ((uint)f2bf(v0.y) << 16);
  p.y = (uint)f2bf(v0.z) | ((uint)f2bf(v0.w) << 16);
  p.z = (uint)f2bf(v1.x) | ((uint)f2bf(v1.y) << 16);
  p.w = (uint)f2bf(v1.z) | ((uint)f2bf(v1.w) << 16);
  reinterpret_cast<uint4*>(wb3)[idx] = p;
}

// ---------------- Cooperative single-pass kernel ----------------
__global__ __launch_bounds__(512, 2) void hyp_coop(const float* __restrict__ x,
                                                   const ushort* __restrict__ wb3,
                                                   float* __restrict__ ssxP,
                                                   float* __restrict__ sspP,
                                                   float* __restrict__ out) {
  __shared__ __align__(16) ushort Abuf[2][32 * 256];  // 2 x 16 KiB swizzled bf16
  __shared__ float sspw[8][256];                      // per-wave ||mx'||^2 partials
  __shared__ float gl[256];                           // per-row gamma

  const int tid = threadIdx.x;
  const int w = tid >> 6;     // wave id == nt
  const int l = tid & 63;
  const int lo = l & 31;
  const int hi = l >> 5;
  const int b = blockIdx.x & 15;
  const int rg = blockIdx.x >> 4;  // 0..31
  const size_t row0 = (size_t)rg * 256;

  // ---- persistent B for nt = w: 16 x 1KB coalesced loads (64 VGPR) ----
  short8 B[16];
  const ushort* bbase = wb3 + ((size_t)b << 16);
#pragma unroll
  for (int kf = 0; kf < 16; ++kf)
    B[kf] = *reinterpret_cast<const short8*>(bbase + (size_t)(kf * 8 + w) * 512 + l * 8);

  // stage mapping: thread -> (row srow, 64B segment seg)
  const int srow = tid >> 4;  // 0..31
  const int seg = tid & 15;
  const float* xsb = x + (row0 + srow) * 4096 + b * 256 + seg * 16;

  uint mx[8][8];  // fp16x2-packed mx' (64 VGPR), static-indexed via full unroll
  float4 va[4];
#pragma unroll
  for (int j = 0; j < 4; ++j) va[j] = *reinterpret_cast<const float4*>(xsb + j * 4);

#pragma unroll
  for (int t = 0; t < 8; ++t) {
    char* A = reinterpret_cast<char*>(Abuf[t & 1]);

    // ---- stage write (bf16, swizzled) + ssx ----
    {
      float ss = 0.f;
#pragma unroll
      for (int j = 0; j < 4; ++j) {
        float4 v = va[j];
        ss += v.x * v.x + v.y * v.y + v.z * v.z + v.w * v.w;
        uint2 p;
        p.x = (uint)f2bf(v.x) | ((uint)f2bf(v.y) << 16);
        p.y = (uint)f2bf(v.z) | ((uint)f2bf(v.w) << 16);
        uint byte = ((uint)(srow * 512 + seg * 32 + j * 8)) ^ ((uint)(srow & 7) << 4);
        *reinterpret_cast<uint2*>(A + byte) = p;
      }
      ss += __shfl_xor(ss, 1, 64);
      ss += __shfl_xor(ss, 2, 64);
      ss += __shfl_xor(ss, 4, 64);
      ss += __shfl_xor(ss, 8, 64);
      if (seg == 0) ssxP[b * 8192 + row0 + t * 32 + srow] = ss;
    }
    __syncthreads();  // A[t] visible

    // ---- prefetch next tile (in flight under compute) ----
    if (t < 7) {
      const float* nx = xsb + (size_t)(t + 1) * 32 * 4096;
#pragma unroll
      for (int j = 0; j < 4; ++j) va[j] = *reinterpret_cast<const float4*>(nx + j * 4);
    }

    // ---- compute: 16 kf x (ds_read_b128 A-frag + 1 MFMA) ----
    f32x16 acc;
#pragma unroll
    for (int r = 0; r < 16; ++r) acc[r] = 0.f;
#pragma unroll
    for (int kf = 0; kf < 16; ++kf) {
      uint ab = ((uint)(lo * 512 + kf * 32 + hi * 16)) ^ ((uint)(lo & 7) << 4);
      short8 af = *reinterpret_cast<const short8*>(A + ab);
      acc = __builtin_amdgcn_mfma_f32_32x32x16_bf16(af, B[kf], acc, 0, 0, 0);
    }

    // ---- pack mx' fp16 (rows stay in this wave's registers) ----
#pragma unroll
    for (int j = 0; j < 8; ++j) {
      __half2 h = __floats2half2_rn(acc[2 * j], acc[2 * j + 1]);
      mx[t][j] = *reinterpret_cast<uint*>(&h);
    }

    // ---- ssp partials over this wave's 32 cols ----
    {
      float s[16];
#pragma unroll
      for (int r = 0; r < 16; ++r) s[r] = acc[r] * acc[r];
#pragma unroll
      for (int m = 1; m < 32; m <<= 1)
#pragma unroll
        for (int r = 0; r < 16; ++r) s[r] += __shfl_xor(s[r], m, 64);
      if (lo == 0) {
#pragma unroll
        for (int r = 0; r < 16; ++r)
          sspw[w][t * 32 + (r & 3) + 8 * (r >> 2) + 4 * hi] = s[r];
      }
    }
    __syncthreads();  // readers of A[t] done; sspw[.][t-slice] complete
  }

  // ---- WG ssp partial -> global ----
  if (tid < 256) {
    float sp = 0.f;
#pragma unroll
    for (int ww = 0; ww < 8; ++ww) sp += sspw[ww][tid];
    sspP[b * 8192 + row0 + tid] = sp;
  }

  cg::this_grid().sync();

  // ---- gamma for this WG's 256 rows (partials L2-hot) ----
  if (tid < 256) {
    const size_t row = row0 + tid;
    float sx = 0.f, s2 = 0.f;
#pragma unroll
    for (int bb = 0; bb < 16; ++bb) {
      sx += ssxP[bb * 8192 + row];
      s2 += sspP[bb * 8192 + row];
    }
    gl[tid] = gamma_of(sx, s2);
  }
  __syncthreads();

  // ---- epilogue: out = gam[row] * mx' (from registers) ----
  const int col = b * 256 + w * 32 + lo;
#pragma unroll
  for (int t = 0; t < 8; ++t) {
#pragma unroll
    for (int j = 0; j < 8; ++j) {
      const int r0 = 2 * j, r1 = 2 * j + 1;
      const int lr0 = t * 32 + (r0 & 3) + 8 * (r0 >> 2) + 4 * hi;
      const int lr1 = t * 32 + (r1 & 3) + 8 * (r1 >> 2) + 4 * hi;
      uint pv = mx[t][j];
      float2 f = __half22float2(*reinterpret_cast<__half2*>(&pv));
      out[(row0 + lr0) * 4096 + col] = f.x * gl[lr0];
      out[(row0 + lr1) * 4096 + col] = f.y * gl[lr1];
    }
  }
}

// ---------------- Fallback: round-9 pipeline ----------------
__global__ __launch_bounds__(256, 2) void k1_kernel(const float* __restrict__ x,
                                                    const ushort* __restrict__ wb3,
                                                    float* __restrict__ ssxP,
                                                    float* __restrict__ sspP,
                                                    ushort* __restrict__ mxw) {
  const int tid = threadIdx.x;
  const int w = tid >> 6;
  const int l = tid & 63;
  const int lo = l & 31;
  const int hi = l >> 5;
  const int b = blockIdx.x & 15;
  const int rg = blockIdx.x >> 4;
  const ushort* bbase = wb3 + ((size_t)b << 16);
  short8 B0[16], B1[16];
#pragma unroll
  for (int kf = 0; kf < 16; ++kf) {
    B0[kf] = *reinterpret_cast<const short8*>(bbase + (size_t)(kf * 8 + w * 2 + 0) * 512 + l * 8);
    B1[kf] = *reinterpret_cast<const short8*>(bbase + (size_t)(kf * 8 + w * 2 + 1) * 512 + l * 8);
  }
  for (int t = 0; t < 8; ++t) {
    const int rt = rg * 8 + t;
    const float* abase = x + ((size_t)rt * 32 + lo) * 4096 + b * 256 + hi * 8;
    f32x16 a0, a1;
#pragma unroll
    for (int r = 0; r < 16; ++r) { a0[r] = 0.f; a1[r] = 0.f; }
    float ssl = 0.f;
#pragma unroll
    for (int bb4 = 0; bb4 < 4; ++bb4) {
      float4 va[8];
#pragma unroll
      for (int k4 = 0; k4 < 4; ++k4) {
        const int kf = bb4 * 4 + k4;
        va[k4 * 2 + 0] = *reinterpret_cast<const float4*>(abase + kf * 16);
        va[k4 * 2 + 1] = *reinterpret_cast<const float4*>(abase + kf * 16 + 4);
      }
      if (w == 0) {
#pragma unroll
        for (int i = 0; i < 8; ++i)
          ssl += va[i].x * va[i].x + va[i].y * va[i].y + va[i].z * va[i].z + va[i].w * va[i].w;
      }
#pragma unroll
      for (int k4 = 0; k4 < 4; ++k4) {
        const int kf = bb4 * 4 + k4;
        const float4 v0 = va[k4 * 2], v1 = va[k4 * 2 + 1];
        short8 af;
        af[0] = (short)f2bf(v0.x); af[1] = (short)f2bf(v0.y);
        af[2] = (short)f2bf(v0.z); af[3] = (short)f2bf(v0.w);
        af[4] = (short)f2bf(v1.x); af[5] = (short)f2bf(v1.y);
        af[6] = (short)f2bf(v1.z); af[7] = (short)f2bf(v1.w);
        a0 = __builtin_amdgcn_mfma_f32_32x32x16_bf16(af, B0[kf], a0, 0, 0, 0);
        a1 = __builtin_amdgcn_mfma_f32_32x32x16_bf16(af, B1[kf], a1, 0, 0, 0);
      }
    }
    if (w == 0) {
      ssl += __shfl_xor(ssl, 32, 64);
      if (hi == 0) ssxP[b * 8192 + rt * 32 + lo] = ssl;
    }
    {
      float s[16];
#pragma unroll
      for (int r = 0; r < 16; ++r) s[r] = a0[r] * a0[r] + a1[r] * a1[r];
#pragma unroll
      for (int m = 1; m < 32; m <<= 1)
#pragma unroll
        for (int r = 0; r < 16; ++r) s[r] += __shfl_xor(s[r], m, 64);
      if (lo == 0) {
#pragma unroll
        for (int r = 0; r < 16; ++r) {
          const int rr = (r & 3) + 8 * (r >> 2) + 4 * hi;
          sspP[(size_t)(b * 4 + w) * 8192 + rt * 32 + rr] = s[r];
        }
      }
    }
    {
      uint wds[16];
#pragma unroll
      for (int j = 0; j < 8; ++j) {
        __half2 h0 = __floats2half2_rn(a0[2 * j], a0[2 * j + 1]);
        __half2 h1 = __floats2half2_rn(a1[2 * j], a1[2 * j + 1]);
        wds[j] = *reinterpret_cast<uint*>(&h0);
        wds[8 + j] = *reinterpret_cast<uint*>(&h1);
      }
      ushort* dst = mxw + (size_t)((b * 256 + rt) * 4 + w) * 2048;
#pragma unroll
      for (int i = 0; i < 4; ++i) {
        uint4 p;
        p.x = wds[i * 4 + 0]; p.y = wds[i * 4 + 1];
        p.z = wds[i * 4 + 2]; p.w = wds[i * 4 + 3];
        *reinterpret_cast<uint4*>(dst + (size_t)(i * 64 + l) * 8) = p;
      }
    }
  }
}

__global__ __launch_bounds__(256) void gamma_kernel(const float* __restrict__ ssxP,
                                                    const float* __restrict__ sspP,
                                                    float* __restrict__ gam) {
  const int row = blockIdx.x * 256 + threadIdx.x;
  float sx = 0.f, s2 = 0.f;
#pragma unroll
  for (int bb = 0; bb < 16; ++bb) sx += ssxP[bb * 8192 + row];
#pragma unroll
  for (int p = 0; p < 64; ++p) s2 += sspP[(size_t)p * 8192 + row];
  gam[row] = gamma_of(sx, s2);
}

__global__ __launch_bounds__(256) void k3_kernel(const ushort* __restrict__ mxw,
                                                 const float* __restrict__ gam,
                                                 float* __restrict__ out) {
  const int wt = blockIdx.x * 4 + (threadIdx.x >> 6);
  const int l = threadIdx.x & 63;
  const int lo = l & 31;
  const int hi = l >> 5;
  const int w = wt & 3;
  const int rt = (wt >> 2) & 255;
  const int b = wt >> 10;
  const ushort* src = mxw + (size_t)wt * 2048;
  uint4 p[4];
#pragma unroll
  for (int i = 0; i < 4; ++i)
    p[i] = *reinterpret_cast<const uint4*>(src + (size_t)(i * 64 + l) * 8);
  const int colbase = b * 256 + w * 64 + lo;
  const int rowb = rt * 32 + 4 * hi;
  const uint* pw = reinterpret_cast<const uint*>(p);
#pragma unroll
  for (int j = 0; j < 8; ++j) {
    const int r0 = 2 * j, r1 = 2 * j + 1;
    const int R0 = rowb + (r0 & 3) + 8 * (r0 >> 2);
    const int R1 = rowb + (r1 & 3) + 8 * (r1 >> 2);
    uint w0 = pw[j];
    uint w1 = pw[8 + j];
    float2 f0 = __half22float2(*reinterpret_cast<__half2*>(&w0));
    float2 f1 = __half22float2(*reinterpret_cast<__half2*>(&w1));
    const float g0 = gam[R0], g1 = gam[R1];
    out[(size_t)R0 * 4096 + colbase] = f0.x * g0;
    out[(size_t)R1 * 4096 + colbase] = f0.y * g1;
    out[(size_t)R0 * 4096 + colbase + 32] = f1.x * g0;
    out[(size_t)R1 * 4096 + colbase + 32] = f1.y * g1;
  }
}

extern "C" void kernel_launch(void* const* d_in, const int* in_sizes, int n_in,
                              void* d_out, int out_size, void* d_ws, size_t ws_size,
                              hipStream_t stream) {
  const float* x = (const float*)d_in[0];  // [4,2048,4096] f32
  const float* w = (const float*)d_in[1];  // [16,256,256] f32
  float* out = (float*)d_out;              // [4,2048,4096] f32

  const size_t WB = (size_t)2 << 20;                   // wb3: 2 MiB @ 0
  const size_t SSX_OFF = WB;                           // ssxP: 512 KiB
  const size_t SSP_OFF = WB + ((size_t)512 << 10);     // sspP: 2 MiB (fallback uses 64 arrays)
  const size_t MXW_OFF = SSP_OFF + ((size_t)2 << 20);  // mxw: 64 MiB (fallback only)
  const size_t NEED_COOP = SSP_OFF + ((size_t)512 << 10);
  const size_t NEED_FULL = MXW_OFF + (size_t)16 * 8192 * 256 * 2;

  ushort* wb3 = (ushort*)d_ws;
  float* ssxP = (float*)((char*)d_ws + SSX_OFF);
  float* sspP = (float*)((char*)d_ws + SSP_OFF);

  int nb = 0;
  bool coop_ok = (hipOccupancyMaxActiveBlocksPerMultiprocessor(&nb, hyp_coop, 512, 0) ==
                  hipSuccess) && nb >= 2;

  if (coop_ok && ws_size >= NEED_COOP) {
    wrepack32<<<512, 256, 0, stream>>>(w, wb3);
    void* args[5] = {(void*)&x, (void*)&wb3, (void*)&ssxP, (void*)&sspP, (void*)&out};
    hipLaunchCooperativeKernel(hyp_coop, dim3(512), dim3(512), args, 0, stream);
  } else if (ws_size >= NEED_FULL) {
    float* gamv = (float*)d_ws;  // overlaps wb3 (dead after K1)
    ushort* mxw = (ushort*)((char*)d_ws + MXW_OFF);
    wrepack32<<<512, 256, 0, stream>>>(w, wb3);
    k1_kernel<<<512, 256, 0, stream>>>(x, wb3, ssxP, sspP, mxw);
    gamma_kernel<<<32, 256, 0, stream>>>(ssxP, sspP, gamv);
    k3_kernel<<<4096, 256, 0, stream>>>(mxw, gamv, out);
  }
}